// Round 6
// baseline (533.660 us; speedup 1.0000x reference)
//
#include <hip/hip_runtime.h>
#include <math.h>

// Problem constants (from reference)
#define Bn    256
#define Tn    1024
#define In    64
#define Pn    256
#define En    128
#define NOUTn 64
#define LN_EPS 1e-5f

// softmax factorization constants (TEMP=8):
// z_j ∝ exp((j-2)*frac/4) * exp(-(j-2)^2/8)  (common exp(-frac^2/8) cancels)
#define C1f 0.3606737602222409f     // log2(e)/4
#define K1f 0.8824969025845955f     // exp(-1/8)
#define K2f 0.6065306597126334f     // exp(-4/8)

typedef float f32x2 __attribute__((ext_vector_type(2)));

__device__ __forceinline__ float tanh_fast(float x) {
    float e = __builtin_amdgcn_exp2f(x * 2.88539008177793f);   // e^(2x)
    return 1.0f - 2.0f * __builtin_amdgcn_rcpf(e + 1.0f);
}
__device__ __forceinline__ f32x2 tanh2(f32x2 x) {
    f32x2 e;
    e[0] = __builtin_amdgcn_exp2f(x[0] * 2.88539008177793f);
    e[1] = __builtin_amdgcn_exp2f(x[1] * 2.88539008177793f);
    f32x2 r;
    r[0] = __builtin_amdgcn_rcpf(e[0] + 1.0f);
    r[1] = __builtin_amdgcn_rcpf(e[1] + 1.0f);
    return 1.0f - 2.0f * r;
}

template<int CTRL, int RMASK>
__device__ __forceinline__ float dpp_add(float x) {
    return x + __int_as_float(__builtin_amdgcn_update_dpp(
        0, __float_as_int(x), CTRL, RMASK, 0xF, false));
}
__device__ __forceinline__ void wave_sum64_x3(float& x, float& y, float& z) {
#define LVL(C, R) x = dpp_add<C, R>(x); y = dpp_add<C, R>(y); z = dpp_add<C, R>(z);
    LVL(0x111, 0xF)
    LVL(0x112, 0xF)
    LVL(0x114, 0xF)
    LVL(0x118, 0xF)
    LVL(0x142, 0xA)
    LVL(0x143, 0xC)
#undef LVL
    x = __int_as_float(__builtin_amdgcn_readlane(__float_as_int(x), 63));
    y = __int_as_float(__builtin_amdgcn_readlane(__float_as_int(y), 63));
    z = __int_as_float(__builtin_amdgcn_readlane(__float_as_int(z), 63));
}

// ===========================================================================
// Pass A: emb4[b][t/4][e][t%4] = tanh(x . W_in[e] + b_in[e])
// Register-tiled GEMM (unchanged from R4/R5: ~80 us).
// ===========================================================================
__global__ __launch_bounds__(256)
void embgemm_kernel(const float* __restrict__ x, const float* __restrict__ W_in,
                    const float* __restrict__ b_in, float* __restrict__ emb4) {
    __shared__ float wlds[128 * 68];
    const int tid = threadIdx.x;
    for (int i = tid; i < 128 * 64; i += 256)
        wlds[(i >> 6) * 68 + (i & 63)] = W_in[i];
    __syncthreads();

    const int b    = blockIdx.x >> 3;
    const int tseg = blockIdx.x & 7;
    const int w    = tid >> 6;
    const int l    = tid & 63;
    const int t0   = tseg * 128 + (w >> 1) * 64 + (l >> 3) * 8;
    const int e0   = (w & 1) * 64 + (l & 7);

    float acc[8][8];
    #pragma unroll
    for (int i = 0; i < 8; ++i)
        #pragma unroll
        for (int j = 0; j < 8; ++j) acc[i][j] = 0.f;

    const float4* xrow = (const float4*)(x + ((size_t)b * Tn + t0) * In);

    for (int i4 = 0; i4 < 16; ++i4) {
        float4 xv[8];
        #pragma unroll
        for (int tt = 0; tt < 8; ++tt) xv[tt] = xrow[tt * 16 + i4];
        float4 wf[8];
        #pragma unroll
        for (int j = 0; j < 8; ++j)
            wf[j] = *(const float4*)&wlds[(e0 + 8 * j) * 68 + i4 * 4];
        #pragma unroll
        for (int tt = 0; tt < 8; ++tt)
            #pragma unroll
            for (int j = 0; j < 8; ++j) {
                acc[tt][j] += xv[tt].x * wf[j].x;
                acc[tt][j] += xv[tt].y * wf[j].y;
                acc[tt][j] += xv[tt].z * wf[j].z;
                acc[tt][j] += xv[tt].w * wf[j].w;
            }
    }

    const int tb0 = t0 >> 2;
    #pragma unroll
    for (int j = 0; j < 8; ++j) {
        const int e = e0 + 8 * j;
        const float be = b_in[e];
        #pragma unroll
        for (int tb = 0; tb < 2; ++tb) {
            float4 o;
            o.x = tanh_fast(acc[tb * 4 + 0][j] + be);
            o.y = tanh_fast(acc[tb * 4 + 1][j] + be);
            o.z = tanh_fast(acc[tb * 4 + 2][j] + be);
            o.w = tanh_fast(acc[tb * 4 + 3][j] + be);
            *(float4*)&emb4[(((size_t)b * 256 + tb0 + tb) * 128 + e) * 4] = o;
        }
    }
}

// ===========================================================================
// Pass B: scan, ONE WAVE per batch, assume-walk canonical state.
// Canonical state {ptr, base, z*, inv, nb*} is staged for the WALK outcome at
// the END of each step (zero-copy fall-through); a prefetched JUMP package
// {jmp_ptr, jmp_base, zJ*, invJ, nbJ*} (LDS reads issued right after the
// scatter, a full step early) lets a jump step be ~16 register overwrites --
// gather latency is fully off the serial chain on BOTH paths.
// ===========================================================================
#define LDSG_FLOATS (Pn * En + Pn)
#define LDSG_BYTES  (LDSG_FLOATS * 4)

__global__ __launch_bounds__(64, 1)
void scan5_kernel(const float* __restrict__ emb4,
                  const float* __restrict__ pointer_init,
                  const float* __restrict__ ln_w, const float* __restrict__ ln_b,
                  const float* __restrict__ jump_dest,
                  const float* __restrict__ Wg,  const float* __restrict__ bg,
                  const float* __restrict__ cs_ptr,
                  const float* __restrict__ Wo,  const float* __restrict__ bo,
                  float* __restrict__ out) {
    extern __shared__ float lds[];
    float* mem = lds;              // ring: [row][2*l + c], channel pair per lane
    float* jd  = lds + Pn * En;    // jump_dest copy

    const int b = blockIdx.x;
    const int l = threadIdx.x;

    float4* m4 = (float4*)mem;
    for (int i = l; i < Pn * En / 4; i += 64) m4[i] = make_float4(0.f, 0.f, 0.f, 0.f);
    for (int i = l; i < Pn; i += 64) jd[i] = jump_dest[i];
    // single wave: DS program order suffices, no barrier needed

    const f32x2 lnw = {ln_w[l], ln_w[l + 64]};
    const f32x2 lnb = {ln_b[l], ln_b[l + 64]};
    const f32x2 wg  = {Wg[l],   Wg[l + 64]};
    const float bgs = bg[0];
    const float cs  = 1.0f / (1.0f + expf(-cs_ptr[0]));
    f32x2 hid = {0.f, 0.f};

    const float4* e40 = (const float4*)(emb4 + ((size_t)b << 17)) + l;   // ch l
    const float4* e41 = e40 + 64;                                        // ch l+64
    float4 A0 = e40[0],   A1 = e41[0];
    float4 B0 = e40[128], B1 = e41[128];

    // ---- canonical (walk-assumed) state: dummy, overwritten by forced jump ----
    float ptr = 0.f; int base = 0;
    float z0 = 0.f, z1 = 0.f, z3 = 0.f, z4 = 0.f, inv = 1.f;   // z2 == 1 always
    f32x2 nb0 = {0,0}, nb1 = {0,0}, nb2 = {0,0}, nb3 = {0,0}, nb4 = {0,0};

    // ---- jump package for step 0: "jump" to pointer_init ----
    float jl      = 1.0f;
    float jmp_ptr = pointer_init[b];
    int   jmp_base = (int)jmp_ptr; jmp_base = jmp_base > 255 ? 255 : jmp_base;
    float zJ0, zJ1, zJ3, zJ4, invJ;
    {
        const float fj = jmp_ptr - (float)jmp_base;
        const float rj  = __builtin_amdgcn_exp2f(fj * C1f);
        const float rji = __builtin_amdgcn_exp2f(-fj * C1f);
        zJ0 = K2f * rji * rji; zJ1 = K1f * rji;
        zJ3 = K1f * rj;        zJ4 = K2f * rj * rj;
        invJ = __builtin_amdgcn_rcpf(((zJ0 + zJ1) + (1.0f + zJ3)) + zJ4);
    }
    f32x2 nbJ0 = {0,0}, nbJ1 = {0,0}, nbJ2 = {0,0}, nbJ3 = {0,0}, nbJ4 = {0,0};
    // ring is all-zero at t=0, so the prefetched jump window is exactly zero.

#define SSTEP(EC0, EC1) {                                                      \
    if (jl > 0.0f) {   /* uniform scalar branch; walk = zero-copy fall-thru */ \
        ptr = jmp_ptr; base = jmp_base;                                        \
        z0 = zJ0; z1 = zJ1; z3 = zJ3; z4 = zJ4; inv = invJ;                    \
        nb0 = nbJ0; nb1 = nbJ1; nb2 = nbJ2; nb3 = nbJ3; nb4 = nbJ4;            \
    }                                                                          \
    const float jtN = jd[base];               /* off-chain, issued early */    \
    float* r0 = mem + (((base + 254) & 255) << 7) + 2 * l;                     \
    float* r1 = mem + (((base + 255) & 255) << 7) + 2 * l;                     \
    float* r2 = mem + ((base) << 7) + 2 * l;                                   \
    float* r3 = mem + (((base + 1) & 255) << 7) + 2 * l;                       \
    float* r4 = mem + (((base + 2) & 255) << 7) + 2 * l;                       \
    const f32x2 ctx = inv * (((nb0 * z0 + nb1 * z1) + (nb2 + nb3 * z3))        \
                             + nb4 * z4);                                      \
    f32x2 em; em[0] = (EC0); em[1] = (EC1);                                    \
    const f32x2 su = tanh2(em + cs * ctx + hid);                               \
    const f32x2 g  = su * inv;                                                 \
    const f32x2 m0v = nb0 + z0 * g, m1v = nb1 + z1 * g, m2v = nb2 + g,         \
                m3v = nb3 + z3 * g, m4v = nb4 + z4 * g;                        \
    *(f32x2*)r0 = m0v; *(f32x2*)r1 = m1v; *(f32x2*)r2 = m2v;                   \
    *(f32x2*)r3 = m3v; *(f32x2*)r4 = m4v;                                      \
    /* walk-stage canonical state for t+1 (no copies on the walk path) */      \
    nb0 = m1v; nb1 = m2v; nb2 = m3v; nb3 = m4v;                                \
    nb4 = *(f32x2*)(mem + (((base + 3) & 255) << 7) + 2 * l);                  \
    ptr = ptr + 1.0f; if (ptr >= 256.0f) ptr -= 256.0f;                        \
    base = (base + 1) & 255;                                                   \
    /* jump package for t+1: reads AFTER the scatter (program order = RAW ok)*/\
    jmp_ptr = jtN;                                                             \
    int bj = (int)jtN; bj = bj > 255 ? 255 : bj;                               \
    jmp_base = bj;                                                             \
    nbJ0 = *(f32x2*)(mem + (((bj + 254) & 255) << 7) + 2 * l);                 \
    nbJ1 = *(f32x2*)(mem + (((bj + 255) & 255) << 7) + 2 * l);                 \
    nbJ2 = *(f32x2*)(mem + ((bj) << 7) + 2 * l);                               \
    nbJ3 = *(f32x2*)(mem + (((bj + 1) & 255) << 7) + 2 * l);                   \
    nbJ4 = *(f32x2*)(mem + (((bj + 2) & 255) << 7) + 2 * l);                   \
    const float fj = jtN - (float)bj;                                          \
    const float rj  = __builtin_amdgcn_exp2f(fj * C1f);                        \
    const float rji = __builtin_amdgcn_exp2f(-fj * C1f);                       \
    zJ0 = K2f * rji * rji; zJ1 = K1f * rji;                                    \
    zJ3 = K1f * rj;        zJ4 = K2f * rj * rj;                                \
    invJ = __builtin_amdgcn_rcpf(((zJ0 + zJ1) + (1.0f + zJ3)) + zJ4);          \
    /* reductions + LN + gate */                                               \
    float s1 = su[0] + su[1];                                                  \
    const f32x2 sq = su * su;  float s2 = sq[0] + sq[1];                       \
    const f32x2 sg = su * wg;  float s3 = sg[0] + sg[1];                       \
    wave_sum64_x3(s1, s2, s3);                                                 \
    const float mu   = s1 * (1.0f / En);                                       \
    const float var  = s2 * (1.0f / En) - mu * mu;                             \
    const float rstd = __builtin_amdgcn_rsqf(var + LN_EPS);                    \
    hid = (su - mu) * rstd * lnw + lnb;                                        \
    jl  = s3 + bgs;                                                            \
}

    for (int tb = 0; tb < 256; ++tb) {
        const int tp = tb + 2 > 255 ? 255 : tb + 2;
        float4 C0 = e40[tp << 7];
        float4 C1 = e41[tp << 7];
        SSTEP(A0.x, A1.x)
        SSTEP(A0.y, A1.y)
        SSTEP(A0.z, A1.z)
        SSTEP(A0.w, A1.w)
        A0 = B0; A1 = B1; B0 = C0; B1 = C1;
    }
#undef SSTEP

    // epilogue: logits = hid @ Wo^T + bo
    mem[l] = hid[0]; mem[64 + l] = hid[1];
    __syncthreads();
    const float4* w4 = (const float4*)(Wo + l * En);
    const float4* h4 = (const float4*)mem;
    float a0 = 0.f, a1 = 0.f, a2 = 0.f, a3 = 0.f;
    #pragma unroll
    for (int i = 0; i < En / 4; ++i) {
        float4 wv = w4[i]; float4 hv = h4[i];
        a0 += wv.x * hv.x; a1 += wv.y * hv.y; a2 += wv.z * hv.z; a3 += wv.w * hv.w;
    }
    out[b * NOUTn + l] = (a0 + a1) + (a2 + a3) + bo[l];
}

// ===========================================================================
// Fallback (ws too small for the 128 MiB emb buffer): round-1 kernel.
// ===========================================================================
#define LDS_FLOATS (Pn*En + 2*En + 2*In + Pn)
#define LDS_BYTES  (LDS_FLOATS * 4)

__global__ __launch_bounds__(192, 1)
void ring_kernel(const float* __restrict__ x,
                 const float* __restrict__ pointer_init,
                 const float* __restrict__ W_in,
                 const float* __restrict__ b_in,
                 const float* __restrict__ ln_w,
                 const float* __restrict__ ln_b,
                 const float* __restrict__ jump_dest,
                 const float* __restrict__ Wg,
                 const float* __restrict__ bg,
                 const float* __restrict__ cs_ptr,
                 const float* __restrict__ Wo,
                 const float* __restrict__ bo,
                 float* __restrict__ out)
{
    extern __shared__ float lds[];
    float* mem  = lds;
    float* embb = mem + Pn * En;
    float* xb   = embb + 2 * En;
    float* jd   = xb + 2 * In;

    const int b   = blockIdx.x;
    const int tid = threadIdx.x;

    for (int i = tid; i < Pn * En; i += 192) mem[i] = 0.0f;
    for (int i = tid; i < Pn;      i += 192) jd[i]  = jump_dest[i];

    const float* xrow = x + (size_t)b * Tn * In;
    if (tid < 64) {
        xb[tid]      = xrow[tid];
        xb[In + tid] = xrow[In + tid];
    }
    __syncthreads();

    if (tid >= 64) {
        const int p = tid - 64;
        float wr[In];
        {
            const float4* w4 = (const float4*)(W_in + p * In);
            #pragma unroll
            for (int i = 0; i < In / 4; ++i) {
                float4 v = w4[i];
                wr[4*i+0] = v.x; wr[4*i+1] = v.y; wr[4*i+2] = v.z; wr[4*i+3] = v.w;
            }
        }
        const float bi = b_in[p];
        {
            float acc = bi;
            #pragma unroll
            for (int i = 0; i < In; ++i) acc += wr[i] * xb[i];
            embb[p] = tanhf(acc);
        }
        __syncthreads();
        for (int t = 0; t < Tn; ++t) {
            if (t + 1 < Tn) {
                const float* xc = xb + ((t + 1) & 1) * In;
                float acc = bi;
                #pragma unroll
                for (int i = 0; i < In; ++i) acc += wr[i] * xc[i];
                embb[((t + 1) & 1) * En + p] = tanhf(acc);
            }
            __syncthreads();
        }
    } else {
        const int l = tid;
        const float lnw0 = ln_w[l],      lnw1 = ln_w[l + 64];
        const float lnb0 = ln_b[l],      lnb1 = ln_b[l + 64];
        const float wg0  = Wg[l],        wg1  = Wg[l + 64];
        const float bgs  = bg[0];
        const float cs   = 1.0f / (1.0f + expf(-cs_ptr[0]));
        float hid0 = 0.0f, hid1 = 0.0f;
        float ptr  = pointer_init[b];
        __syncthreads();

        for (int t = 0; t < Tn; ++t) {
            const bool do_stage = (t + 2 < Tn);
            float xs = 0.0f;
            if (do_stage) xs = xrow[(t + 2) * In + l];

            const float* embc = embb + (t & 1) * En;

            int base = (int)floorf(ptr);
            base = base < 0 ? 0 : (base > Pn - 1 ? Pn - 1 : base);
            int cur = (int)ptr;
            cur = cur < 0 ? 0 : (cur > Pn - 1 ? Pn - 1 : cur);
            const float jt = jd[cur];

            const float frac = ptr - (float)base;
            int   idx[5];
            float wgt[5];
            float mx = -3.4e38f;
            #pragma unroll
            for (int j = 0; j < 5; ++j) {
                idx[j] = (base + j - 2 + Pn) & (Pn - 1);
                float d = (float)(j - 2) - frac;
                float s = -(d * d) * 0.125f;
                wgt[j] = s;
                mx = fmaxf(mx, s);
            }
            float se = 0.0f;
            #pragma unroll
            for (int j = 0; j < 5; ++j) { float ez = expf(wgt[j] - mx); wgt[j] = ez; se += ez; }
            const float inv = 1.0f / se;

            float nb0[5], nb1[5];
            #pragma unroll
            for (int j = 0; j < 5; ++j) {
                nb0[j] = mem[idx[j] * En + l];
                nb1[j] = mem[idx[j] * En + 64 + l];
            }
            float ctx0 = 0.0f, ctx1 = 0.0f;
            #pragma unroll
            for (int j = 0; j < 5; ++j) {
                const float w = wgt[j] * inv; wgt[j] = w;
                ctx0 += w * nb0[j];
                ctx1 += w * nb1[j];
            }

            const float su0 = tanhf(embc[l]      + cs * ctx0 + hid0);
            const float su1 = tanhf(embc[l + 64] + cs * ctx1 + hid1);

            #pragma unroll
            for (int j = 0; j < 5; ++j) {
                mem[idx[j] * En + l]      = nb0[j] + wgt[j] * su0;
                mem[idx[j] * En + 64 + l] = nb1[j] + wgt[j] * su1;
            }

            float s1 = su0 + su1;
            float s2 = su0 * su0 + su1 * su1;
            float s3 = su0 * wg0 + su1 * wg1;
            #pragma unroll
            for (int off = 32; off > 0; off >>= 1) {
                s1 += __shfl_xor(s1, off, 64);
                s2 += __shfl_xor(s2, off, 64);
                s3 += __shfl_xor(s3, off, 64);
            }

            const float mu   = s1 * (1.0f / En);
            const float var  = s2 * (1.0f / En) - mu * mu;
            const float rstd = rsqrtf(var + LN_EPS);
            hid0 = (su0 - mu) * rstd * lnw0 + lnb0;
            hid1 = (su1 - mu) * rstd * lnw1 + lnb1;

            const float jl = s3 + bgs;
            float walk = ptr + 1.0f;
            if (walk >= 256.0f) walk -= 256.0f;
            ptr = (jl > 0.0f) ? jt : walk;

            if (do_stage) xb[(t & 1) * In + l] = xs;
            __syncthreads();
        }
        embb[l]      = hid0;
        embb[l + 64] = hid1;
    }
    __syncthreads();

    if (tid < NOUTn) {
        const float* wrow = Wo + tid * En;
        float acc = bo[tid];
        #pragma unroll 4
        for (int e = 0; e < En; ++e) acc += embb[e] * wrow[e];
        out[b * NOUTn + tid] = acc;
    }
}

extern "C" void kernel_launch(void* const* d_in, const int* in_sizes, int n_in,
                              void* d_out, int out_size, void* d_ws, size_t ws_size,
                              hipStream_t stream) {
    const float* x            = (const float*)d_in[0];
    const float* pointer_init = (const float*)d_in[1];
    const float* W_in         = (const float*)d_in[2];
    const float* b_in         = (const float*)d_in[3];
    const float* ln_w         = (const float*)d_in[4];
    const float* ln_b         = (const float*)d_in[5];
    const float* jump_dest    = (const float*)d_in[6];
    const float* Wg           = (const float*)d_in[7];
    const float* bg           = (const float*)d_in[8];
    const float* cs           = (const float*)d_in[9];
    const float* Wo           = (const float*)d_in[10];
    const float* bo           = (const float*)d_in[11];
    float* out = (float*)d_out;

    const size_t emb_bytes = (size_t)Bn * Tn * En * sizeof(float);   // 128 MiB

    if (ws_size >= emb_bytes) {
        float* emb4 = (float*)d_ws;
        embgemm_kernel<<<Bn * 8, 256, 0, stream>>>(x, W_in, b_in, emb4);
        (void)hipFuncSetAttribute((const void*)scan5_kernel,
                                  hipFuncAttributeMaxDynamicSharedMemorySize, LDSG_BYTES);
        scan5_kernel<<<Bn, 64, LDSG_BYTES, stream>>>(
            emb4, pointer_init, ln_w, ln_b, jump_dest, Wg, bg, cs, Wo, bo, out);
    } else {
        (void)hipFuncSetAttribute((const void*)ring_kernel,
                                  hipFuncAttributeMaxDynamicSharedMemorySize, LDS_BYTES);
        ring_kernel<<<Bn, 192, LDS_BYTES, stream>>>(
            x, pointer_init, W_in, b_in, ln_w, ln_b, jump_dest, Wg, bg, cs, Wo, bo, out);
    }
}